// Round 10
// baseline (707.182 us; speedup 1.0000x reference)
//
#include <hip/hip_runtime.h>
#include <cstdint>
#include <cstddef>

#define NB 4
#define NQ 8192
#define ND 256
#define NH 8
#define NL 4
#define NP 4
#define PQB 32   // queries per proj block
#define OQB 64   // queries per out block
// HD = 32

// ---------------- transpose (B, D, HW) -> (B, HW, D) ----------------
__global__ __launch_bounds__(256) void transpose_k(
    const float* __restrict__ in, float* __restrict__ out, int HW) {
  __shared__ float tile[32][33];
  int yx0 = blockIdx.x << 5;
  int d0  = blockIdx.y << 5;
  int b   = blockIdx.z;
  const float* inb = in + (size_t)b * ND * HW;
  float* outb = out + (size_t)b * HW * ND;
  int col = threadIdx.x & 31;
  int row = threadIdx.x >> 5;  // 0..7
#pragma unroll
  for (int r = 0; r < 4; ++r) {
    int d = row + (r << 3);
    tile[d][col] = inb[(size_t)(d0 + d) * HW + (yx0 + col)];
  }
  __syncthreads();
#pragma unroll
  for (int r = 0; r < 4; ++r) {
    int y = row + (r << 3);
    outb[(size_t)(yx0 + y) * ND + (d0 + col)] = tile[col][y];
  }
}

// ---------------- proj v3: SGPR-broadcast GEMM, no LDS in inner loop -------
// block = 256 threads = 4 waves, PQB=32 queries.
// wave 0: offsets GEMM queries q0+0..15   (64 lanes x 4 cols = 256 cols)
// wave 1: offsets GEMM queries q0+16..31
// wave 2: attn   GEMM queries q0+0..15   (64 lanes x 2 cols = 128 cols)
// wave 3: attn   GEMM queries q0+16..31
// q-values are wave-uniform -> s_load; FMA uses SGPR operand. LDS only for
// the softmax stage.
__global__ __launch_bounds__(256) void proj_k(
    const float* __restrict__ query, const float* __restrict__ refp,
    const float* __restrict__ W_off, const float* __restrict__ b_off,
    const float* __restrict__ W_attn, const float* __restrict__ b_attn,
    float* __restrict__ pos, float* __restrict__ attn_out) {
  int q0 = blockIdx.x * PQB;
  __shared__ float lg[PQB][128];
  int t = threadIdx.x;
  int wave = t >> 6, lane = t & 63;
  if (wave < 2) {
    const float* qb = query + (size_t)(q0 + wave * 16) * ND;
    int j0 = lane << 2;
    float4 bb = *(const float4*)(b_off + j0);
    float4 acc[16];
#pragma unroll
    for (int qq = 0; qq < 16; ++qq) acc[qq] = bb;
#pragma unroll 2
    for (int k = 0; k < ND; ++k) {
      float4 w = *(const float4*)(W_off + (size_t)k * 256 + j0);
#pragma unroll
      for (int qq = 0; qq < 16; ++qq) {
        float qv = qb[qq * ND + k];
        acc[qq].x = fmaf(qv, w.x, acc[qq].x);
        acc[qq].y = fmaf(qv, w.y, acc[qq].y);
        acc[qq].z = fmaf(qv, w.z, acc[qq].z);
        acc[qq].w = fmaf(qv, w.w, acc[qq].w);
      }
    }
#pragma unroll
    for (int qq = 0; qq < 16; ++qq) {
      int bq = q0 + wave * 16 + qq;
      float rx = refp[bq * 2 + 0] * 2.f - 1.f;
      float ry = refp[bq * 2 + 1] * 2.f - 1.f;
      float4 r;
      r.x = rx + tanhf(acc[qq].x);
      r.y = ry + tanhf(acc[qq].y);
      r.z = rx + tanhf(acc[qq].z);
      r.w = ry + tanhf(acc[qq].w);
      *(float4*)(pos + (size_t)bq * 256 + j0) = r;
    }
  } else {
    const float* qb = query + (size_t)(q0 + (wave - 2) * 16) * ND;
    int j0 = lane << 1;
    float2 bb = *(const float2*)(b_attn + j0);
    float2 acc[16];
#pragma unroll
    for (int qq = 0; qq < 16; ++qq) acc[qq] = bb;
#pragma unroll 2
    for (int k = 0; k < ND; ++k) {
      float2 w = *(const float2*)(W_attn + (size_t)k * 128 + j0);
#pragma unroll
      for (int qq = 0; qq < 16; ++qq) {
        float qv = qb[qq * ND + k];
        acc[qq].x = fmaf(qv, w.x, acc[qq].x);
        acc[qq].y = fmaf(qv, w.y, acc[qq].y);
      }
    }
#pragma unroll
    for (int qq = 0; qq < 16; ++qq) {
      int qi = (wave - 2) * 16 + qq;
      *(float2*)&lg[qi][j0] = acc[qq];
    }
  }
  __syncthreads();
  {
    // softmax: 256 threads, one (q,h) row of 16 each
    int qi = t >> 3, h = t & 7;
    float* l = &lg[qi][h * 16];
    float m = -1e30f;
#pragma unroll
    for (int i = 0; i < 16; ++i) m = fmaxf(m, l[i]);
    float e[16], s = 0.f;
#pragma unroll
    for (int i = 0; i < 16; ++i) { e[i] = __expf(l[i] - m); s += e[i]; }
    float inv = 1.f / s;
#pragma unroll
    for (int i = 0; i < 16; ++i) l[i] = e[i] * inv;
  }
  __syncthreads();
  {
    // coalesced copy-out: PQB*128 floats = 1024 float4 by 256 threads
    const float4* src = (const float4*)&lg[0][0];
    float4* dst = (float4*)(attn_out + (size_t)q0 * 128);
#pragma unroll
    for (int i = 0; i < 4; ++i) dst[t + 256 * i] = src[t + 256 * i];
  }
}

// ---------------- sampling v2: 4 queries/block, LDS sample table ----------
#define HPAD 136  // 16 samples * 8 dwords + 8 pad
__global__ __launch_bounds__(256) void sample_k(
    const float* __restrict__ feat_ws, const float* __restrict__ pos,
    const float* __restrict__ attnw, float* __restrict__ agg) {
  __shared__ int tbl[4 * NH * HPAD];
  int bid = blockIdx.x;
  int wk = ((bid & 7) << 10) | (bid >> 3);  // XCD swizzle: grid 8192 = 8*1024
  int q0 = wk << 2;                          // 4 queries per block
  int b = wk >> 11;                          // batch (8192 q / batch)
  int t = threadIdx.x;

  const int FT1 = NB * 16384 * ND;
  const int FT2 = FT1 + NB * 4096 * ND;
  const int FT3 = FT2 + NB * 1024 * ND;
  int lb[4] = {b * 16384 * ND, FT1 + b * 4096 * ND, FT2 + b * 1024 * ND,
               FT3 + b * 256 * ND};

#pragma unroll
  for (int j = t; j < 512; j += 256) {
    int qi = j >> 7, i = j & 127;  // i = h*16 + l*4 + p
    int bq = q0 + qi;
    float gx = pos[(size_t)bq * 256 + 2 * i];
    float gy = pos[(size_t)bq * 256 + 2 * i + 1];
    float a = attnw[(size_t)bq * 128 + i];
    int l = (i >> 2) & 3;
    int Wf = 128 >> l;
    float wf1 = (float)(Wf - 1);
    float x = (gx + 1.f) * 0.5f * wf1;
    float y = (gy + 1.f) * 0.5f * wf1;
    float x0f = floorf(x), y0f = floorf(y);
    float wx1 = x - x0f, wx0 = 1.f - wx1;
    float wy1 = y - y0f, wy0 = 1.f - wy1;
    int x0 = (int)x0f, y0 = (int)y0f;
    int x1 = x0 + 1, y1 = y0 + 1;
    bool vx0 = (x0 >= 0) && (x0 < Wf);
    bool vx1 = (x1 >= 0) && (x1 < Wf);
    bool vy0 = (y0 >= 0) && (y0 < Wf);
    bool vy1 = (y1 >= 0) && (y1 < Wf);
    int xc0 = min(max(x0, 0), Wf - 1), xc1 = min(max(x1, 0), Wf - 1);
    int yc0 = min(max(y0, 0), Wf - 1), yc1 = min(max(y1, 0), Wf - 1);
    int base = lb[l];
    int o00 = base + (yc0 * Wf + xc0) * ND;
    int o10 = base + (yc0 * Wf + xc1) * ND;
    int o01 = base + (yc1 * Wf + xc0) * ND;
    int o11 = base + (yc1 * Wf + xc1) * ND;
    float w00 = (vx0 && vy0) ? a * wx0 * wy0 : 0.f;
    float w10 = (vx1 && vy0) ? a * wx1 * wy0 : 0.f;
    float w01 = (vx0 && vy1) ? a * wx0 * wy1 : 0.f;
    float w11 = (vx1 && vy1) ? a * wx1 * wy1 : 0.f;
    int h = i >> 4, s = i & 15;
    int* rec = &tbl[(qi * NH + h) * HPAD + s * 8];
    rec[0] = o00; rec[1] = __float_as_int(w00);
    rec[2] = o10; rec[3] = __float_as_int(w10);
    rec[4] = o01; rec[5] = __float_as_int(w01);
    rec[6] = o11; rec[7] = __float_as_int(w11);
  }
  __syncthreads();

  int lane = t & 63, qi = t >> 6;
  int h = lane >> 3, cq = lane & 7;
  int bq = q0 + qi;
  int choff = (h << 5) + (cq << 2);
  const int* rec = &tbl[(qi * NH + h) * HPAD];
  float4 acc = {0.f, 0.f, 0.f, 0.f};
#pragma unroll 4
  for (int s = 0; s < 16; ++s) {
#pragma unroll
    for (int c = 0; c < 4; ++c) {
      int off = rec[s * 8 + c * 2];
      float w = __int_as_float(rec[s * 8 + c * 2 + 1]);
      float4 v = *(const float4*)(feat_ws + off + choff);
      acc.x = fmaf(w, v.x, acc.x);
      acc.y = fmaf(w, v.y, acc.y);
      acc.z = fmaf(w, v.z, acc.z);
      acc.w = fmaf(w, v.w, acc.w);
    }
  }
  *(float4*)(agg + (size_t)bq * 256 + choff) = acc;
}

// ---------------- out v3: SGPR-broadcast GEMM, no LDS ---------------------
// block = 256 threads = 4 waves; wave w handles queries q0+w*16..+15,
// 64 lanes x 4 cols = full 256-col row. agg row addrs wave-uniform -> s_load.
__global__ __launch_bounds__(256) void out_k(
    const float* __restrict__ agg, const float* __restrict__ W_out,
    const float* __restrict__ b_out, float* __restrict__ out) {
  int q0 = blockIdx.x * OQB;
  int t = threadIdx.x;
  int wave = t >> 6, lane = t & 63;
  const float* ab = agg + (size_t)(q0 + wave * 16) * ND;
  int j0 = lane << 2;
  float4 bb = *(const float4*)(b_out + j0);
  float4 acc[16];
#pragma unroll
  for (int qq = 0; qq < 16; ++qq) acc[qq] = bb;
#pragma unroll 2
  for (int k = 0; k < ND; ++k) {
    float4 w = *(const float4*)(W_out + (size_t)k * 256 + j0);
#pragma unroll
    for (int qq = 0; qq < 16; ++qq) {
      float av = ab[qq * ND + k];
      acc[qq].x = fmaf(av, w.x, acc[qq].x);
      acc[qq].y = fmaf(av, w.y, acc[qq].y);
      acc[qq].z = fmaf(av, w.z, acc[qq].z);
      acc[qq].w = fmaf(av, w.w, acc[qq].w);
    }
  }
#pragma unroll
  for (int qq = 0; qq < 16; ++qq) {
    *(float4*)(out + (size_t)(q0 + wave * 16 + qq) * 256 + j0) = acc[qq];
  }
}

extern "C" void kernel_launch(void* const* d_in, const int* in_sizes, int n_in,
                              void* d_out, int out_size, void* d_ws,
                              size_t ws_size, hipStream_t stream) {
  const float* query  = (const float*)d_in[0];
  const float* feat0  = (const float*)d_in[1];
  const float* feat1  = (const float*)d_in[2];
  const float* feat2  = (const float*)d_in[3];
  const float* feat3  = (const float*)d_in[4];
  const float* refp   = (const float*)d_in[5];
  const float* W_off  = (const float*)d_in[6];
  const float* b_off  = (const float*)d_in[7];
  const float* W_attn = (const float*)d_in[8];
  const float* b_attn = (const float*)d_in[9];
  const float* W_out  = (const float*)d_in[10];
  const float* b_out  = (const float*)d_in[11];

  float* out = (float*)d_out;                      // (B, Q, D)
  float* attn_out = out + (size_t)NB * NQ * ND;    // (B, Q, H, L, P)

  float* ws  = (float*)d_ws;
  float* fT0 = ws;                                     // unified feature ws
  float* fT1 = fT0 + (size_t)NB * 16384 * ND;
  float* fT2 = fT1 + (size_t)NB * 4096 * ND;
  float* fT3 = fT2 + (size_t)NB * 1024 * ND;
  float* pos = fT3 + (size_t)NB * 256 * ND;            // 4*8192*256
  float* agg = pos + (size_t)NB * NQ * ND;             // 4*8192*256

  transpose_k<<<dim3(512, 8, NB), 256, 0, stream>>>(feat0, fT0, 16384);
  transpose_k<<<dim3(128, 8, NB), 256, 0, stream>>>(feat1, fT1, 4096);
  transpose_k<<<dim3(32, 8, NB), 256, 0, stream>>>(feat2, fT2, 1024);
  transpose_k<<<dim3(8, 8, NB), 256, 0, stream>>>(feat3, fT3, 256);

  proj_k<<<dim3(NB * NQ / PQB), 256, 0, stream>>>(query, refp, W_off, b_off,
                                                  W_attn, b_attn, pos,
                                                  attn_out);
  sample_k<<<dim3(NB * NQ / 4), 256, 0, stream>>>(fT0, pos, attn_out, agg);
  out_k<<<dim3(NB * NQ / OQB), 256, 0, stream>>>(agg, W_out, b_out, out);
}

// Round 12
// 463.479 us; speedup vs baseline: 1.5258x; 1.5258x over previous
//
#include <hip/hip_runtime.h>
#include <cstdint>
#include <cstddef>

#define NB 4
#define NQ 8192
#define ND 256
#define NH 8
#define NL 4
#define NP 4
#define PQB 32   // queries per proj block
#define OQB 64   // queries per out block
// HD = 32

__device__ __forceinline__ void fma4(float4& acc, float s, const float4& v) {
  acc.x = fmaf(s, v.x, acc.x);
  acc.y = fmaf(s, v.y, acc.y);
  acc.z = fmaf(s, v.z, acc.z);
  acc.w = fmaf(s, v.w, acc.w);
}

// ---------------- transpose (B, D, HW) -> (B, HW, D) ----------------
__global__ __launch_bounds__(256) void transpose_k(
    const float* __restrict__ in, float* __restrict__ out, int HW) {
  __shared__ float tile[32][33];
  int yx0 = blockIdx.x << 5;
  int d0  = blockIdx.y << 5;
  int b   = blockIdx.z;
  const float* inb = in + (size_t)b * ND * HW;
  float* outb = out + (size_t)b * HW * ND;
  int col = threadIdx.x & 31;
  int row = threadIdx.x >> 5;  // 0..7
#pragma unroll
  for (int r = 0; r < 4; ++r) {
    int d = row + (r << 3);
    tile[d][col] = inb[(size_t)(d0 + d) * HW + (yx0 + col)];
  }
  __syncthreads();
#pragma unroll
  for (int r = 0; r < 4; ++r) {
    int y = row + (r << 3);
    outb[(size_t)(yx0 + y) * ND + (d0 + col)] = tile[col][y];
  }
}

// ---------------- proj v4: LDS-staged q, ds_read_b128, 8q x 8c per thread --
// block = 256 threads, PQB=32 queries.
// t<128 : offsets GEMM. slot=t&31 -> cols {c0..c0+3, c0+128..c0+131},
//         qg=t>>5 -> queries qg*8..+7. 256 FMA per 8 LDS b128 per k4.
// t>=128: attn GEMM. slot -> cols c0..c0+3, qg -> queries qg*8..+7.
// q reads are wave-broadcast (<=2 distinct addrs/wave) -> conflict-free.
__global__ __launch_bounds__(256) void proj_k(
    const float* __restrict__ query, const float* __restrict__ refp,
    const float* __restrict__ W_off, const float* __restrict__ b_off,
    const float* __restrict__ W_attn, const float* __restrict__ b_attn,
    float* __restrict__ pos, float* __restrict__ attn_out) {
  int q0 = blockIdx.x * PQB;
  __shared__ float qs[PQB][ND];   // 32 KB
  __shared__ float lg[PQB][132];  // padded: softmax reads spread over banks
  int t = threadIdx.x;
  {
    const float4* src = (const float4*)(query + (size_t)q0 * ND);
    float4* dst = (float4*)&qs[0][0];
#pragma unroll
    for (int i = 0; i < 8; ++i) dst[t + 256 * i] = src[t + 256 * i];
  }
  __syncthreads();
  if (t < 128) {
    int slot = t & 31, qg = t >> 5;
    int c0 = slot << 2;
    const float* qrow = &qs[qg * 8][0];
    const float* wb = W_off + c0;
    float4 b0 = *(const float4*)(b_off + c0);
    float4 b1 = *(const float4*)(b_off + c0 + 128);
    float4 accA[8], accB[8];
#pragma unroll
    for (int qq = 0; qq < 8; ++qq) { accA[qq] = b0; accB[qq] = b1; }
    for (int k = 0; k < ND; k += 4) {
      float4 w0[4], w1[4];
#pragma unroll
      for (int r = 0; r < 4; ++r) {
        w0[r] = *(const float4*)(wb + (size_t)(k + r) * 256);
        w1[r] = *(const float4*)(wb + (size_t)(k + r) * 256 + 128);
      }
#pragma unroll
      for (int qq = 0; qq < 8; ++qq) {
        float4 qv = *(const float4*)(qrow + qq * ND + k);
        fma4(accA[qq], qv.x, w0[0]);
        fma4(accA[qq], qv.y, w0[1]);
        fma4(accA[qq], qv.z, w0[2]);
        fma4(accA[qq], qv.w, w0[3]);
        fma4(accB[qq], qv.x, w1[0]);
        fma4(accB[qq], qv.y, w1[1]);
        fma4(accB[qq], qv.z, w1[2]);
        fma4(accB[qq], qv.w, w1[3]);
      }
    }
#pragma unroll
    for (int qq = 0; qq < 8; ++qq) {
      int bq = q0 + qg * 8 + qq;
      float rx = refp[bq * 2 + 0] * 2.f - 1.f;
      float ry = refp[bq * 2 + 1] * 2.f - 1.f;
      float4 rA, rB;
      rA.x = rx + tanhf(accA[qq].x);
      rA.y = ry + tanhf(accA[qq].y);
      rA.z = rx + tanhf(accA[qq].z);
      rA.w = ry + tanhf(accA[qq].w);
      rB.x = rx + tanhf(accB[qq].x);
      rB.y = ry + tanhf(accB[qq].y);
      rB.z = rx + tanhf(accB[qq].z);
      rB.w = ry + tanhf(accB[qq].w);
      *(float4*)(pos + (size_t)bq * 256 + c0) = rA;
      *(float4*)(pos + (size_t)bq * 256 + c0 + 128) = rB;
    }
  } else {
    int u = t - 128;
    int slot = u & 31, qg = u >> 5;
    int c0 = slot << 2;
    const float* qrow = &qs[qg * 8][0];
    const float* wb = W_attn + c0;
    float4 b0 = *(const float4*)(b_attn + c0);
    float4 acc[8];
#pragma unroll
    for (int qq = 0; qq < 8; ++qq) acc[qq] = b0;
    for (int k = 0; k < ND; k += 4) {
      float4 w[4];
#pragma unroll
      for (int r = 0; r < 4; ++r) {
        w[r] = *(const float4*)(wb + (size_t)(k + r) * 128);
      }
#pragma unroll
      for (int qq = 0; qq < 8; ++qq) {
        float4 qv = *(const float4*)(qrow + qq * ND + k);
        fma4(acc[qq], qv.x, w[0]);
        fma4(acc[qq], qv.y, w[1]);
        fma4(acc[qq], qv.z, w[2]);
        fma4(acc[qq], qv.w, w[3]);
      }
    }
#pragma unroll
    for (int qq = 0; qq < 8; ++qq) {
      *(float4*)&lg[qg * 8 + qq][c0] = acc[qq];
    }
  }
  __syncthreads();
  {
    // softmax: 256 threads, one (q,h) row of 16 each
    int qi = t >> 3, h = t & 7;
    float* l = &lg[qi][h * 16];
    float m = -1e30f;
#pragma unroll
    for (int i = 0; i < 16; ++i) m = fmaxf(m, l[i]);
    float e[16], s = 0.f;
#pragma unroll
    for (int i = 0; i < 16; ++i) { e[i] = __expf(l[i] - m); s += e[i]; }
    float inv = 1.f / s;
#pragma unroll
    for (int i = 0; i < 16; ++i) l[i] = e[i] * inv;
  }
  __syncthreads();
  {
    // coalesced copy-out (skip the 4-float row pad): row = 33 float4
    float4* dst = (float4*)(attn_out + (size_t)q0 * 128);
    const float4* lgf = (const float4*)&lg[0][0];
#pragma unroll
    for (int i = 0; i < 4; ++i) {
      int idx = t + 256 * i;
      int qi = idx >> 5, c4 = idx & 31;
      dst[idx] = lgf[qi * 33 + c4];
    }
  }
}

// ---------------- sampling v2: 4 queries/block, LDS sample table ----------
#define HPAD 136  // 16 samples * 8 dwords + 8 pad
__global__ __launch_bounds__(256) void sample_k(
    const float* __restrict__ feat_ws, const float* __restrict__ pos,
    const float* __restrict__ attnw, float* __restrict__ agg) {
  __shared__ int tbl[4 * NH * HPAD];
  int bid = blockIdx.x;
  int wk = ((bid & 7) << 10) | (bid >> 3);  // XCD swizzle: grid 8192 = 8*1024
  int q0 = wk << 2;                          // 4 queries per block
  int b = wk >> 11;                          // batch (8192 q / batch)
  int t = threadIdx.x;

  const int FT1 = NB * 16384 * ND;
  const int FT2 = FT1 + NB * 4096 * ND;
  const int FT3 = FT2 + NB * 1024 * ND;
  int lb[4] = {b * 16384 * ND, FT1 + b * 4096 * ND, FT2 + b * 1024 * ND,
               FT3 + b * 256 * ND};

#pragma unroll
  for (int j = t; j < 512; j += 256) {
    int qi = j >> 7, i = j & 127;  // i = h*16 + l*4 + p
    int bq = q0 + qi;
    float gx = pos[(size_t)bq * 256 + 2 * i];
    float gy = pos[(size_t)bq * 256 + 2 * i + 1];
    float a = attnw[(size_t)bq * 128 + i];
    int l = (i >> 2) & 3;
    int Wf = 128 >> l;
    float wf1 = (float)(Wf - 1);
    float x = (gx + 1.f) * 0.5f * wf1;
    float y = (gy + 1.f) * 0.5f * wf1;
    float x0f = floorf(x), y0f = floorf(y);
    float wx1 = x - x0f, wx0 = 1.f - wx1;
    float wy1 = y - y0f, wy0 = 1.f - wy1;
    int x0 = (int)x0f, y0 = (int)y0f;
    int x1 = x0 + 1, y1 = y0 + 1;
    bool vx0 = (x0 >= 0) && (x0 < Wf);
    bool vx1 = (x1 >= 0) && (x1 < Wf);
    bool vy0 = (y0 >= 0) && (y0 < Wf);
    bool vy1 = (y1 >= 0) && (y1 < Wf);
    int xc0 = min(max(x0, 0), Wf - 1), xc1 = min(max(x1, 0), Wf - 1);
    int yc0 = min(max(y0, 0), Wf - 1), yc1 = min(max(y1, 0), Wf - 1);
    int base = lb[l];
    int o00 = base + (yc0 * Wf + xc0) * ND;
    int o10 = base + (yc0 * Wf + xc1) * ND;
    int o01 = base + (yc1 * Wf + xc0) * ND;
    int o11 = base + (yc1 * Wf + xc1) * ND;
    float w00 = (vx0 && vy0) ? a * wx0 * wy0 : 0.f;
    float w10 = (vx1 && vy0) ? a * wx1 * wy0 : 0.f;
    float w01 = (vx0 && vy1) ? a * wx0 * wy1 : 0.f;
    float w11 = (vx1 && vy1) ? a * wx1 * wy1 : 0.f;
    int h = i >> 4, s = i & 15;
    int* rec = &tbl[(qi * NH + h) * HPAD + s * 8];
    rec[0] = o00; rec[1] = __float_as_int(w00);
    rec[2] = o10; rec[3] = __float_as_int(w10);
    rec[4] = o01; rec[5] = __float_as_int(w01);
    rec[6] = o11; rec[7] = __float_as_int(w11);
  }
  __syncthreads();

  int lane = t & 63, qi = t >> 6;
  int h = lane >> 3, cq = lane & 7;
  int bq = q0 + qi;
  int choff = (h << 5) + (cq << 2);
  const int* rec = &tbl[(qi * NH + h) * HPAD];
  float4 acc = {0.f, 0.f, 0.f, 0.f};
#pragma unroll 4
  for (int s = 0; s < 16; ++s) {
#pragma unroll
    for (int c = 0; c < 4; ++c) {
      int off = rec[s * 8 + c * 2];
      float w = __int_as_float(rec[s * 8 + c * 2 + 1]);
      float4 v = *(const float4*)(feat_ws + off + choff);
      acc.x = fmaf(w, v.x, acc.x);
      acc.y = fmaf(w, v.y, acc.y);
      acc.z = fmaf(w, v.z, acc.z);
      acc.w = fmaf(w, v.w, acc.w);
    }
  }
  *(float4*)(agg + (size_t)bq * 256 + choff) = acc;
}

// ---------------- out v4: LDS-staged agg, ds_read_b128, 8q x 8c -----------
// block = 256 threads, OQB=64 queries. slot=t&31 -> cols {c0,c0+128} quads,
// qg=t>>5 (0..7) -> queries qg*8..+7.
__global__ __launch_bounds__(256) void out_k(
    const float* __restrict__ agg, const float* __restrict__ W_out,
    const float* __restrict__ b_out, float* __restrict__ out) {
  int q0 = blockIdx.x * OQB;
  __shared__ float as_[OQB][ND];  // 64 KB
  int t = threadIdx.x;
  {
    const float4* src = (const float4*)(agg + (size_t)q0 * ND);
    float4* dst = (float4*)&as_[0][0];
#pragma unroll
    for (int i = 0; i < 16; ++i) dst[t + 256 * i] = src[t + 256 * i];
  }
  __syncthreads();
  int slot = t & 31, qg = t >> 5;
  int c0 = slot << 2;
  const float* arow = &as_[qg * 8][0];
  const float* wb = W_out + c0;
  float4 b0 = *(const float4*)(b_out + c0);
  float4 b1 = *(const float4*)(b_out + c0 + 128);
  float4 accA[8], accB[8];
#pragma unroll
  for (int qq = 0; qq < 8; ++qq) { accA[qq] = b0; accB[qq] = b1; }
  for (int k = 0; k < ND; k += 4) {
    float4 w0[4], w1[4];
#pragma unroll
    for (int r = 0; r < 4; ++r) {
      w0[r] = *(const float4*)(wb + (size_t)(k + r) * 256);
      w1[r] = *(const float4*)(wb + (size_t)(k + r) * 256 + 128);
    }
#pragma unroll
    for (int qq = 0; qq < 8; ++qq) {
      float4 av = *(const float4*)(arow + qq * ND + k);
      fma4(accA[qq], av.x, w0[0]);
      fma4(accA[qq], av.y, w0[1]);
      fma4(accA[qq], av.z, w0[2]);
      fma4(accA[qq], av.w, w0[3]);
      fma4(accB[qq], av.x, w1[0]);
      fma4(accB[qq], av.y, w1[1]);
      fma4(accB[qq], av.z, w1[2]);
      fma4(accB[qq], av.w, w1[3]);
    }
  }
#pragma unroll
  for (int qq = 0; qq < 8; ++qq) {
    int bq = q0 + qg * 8 + qq;
    *(float4*)(out + (size_t)bq * 256 + c0) = accA[qq];
    *(float4*)(out + (size_t)bq * 256 + c0 + 128) = accB[qq];
  }
}

extern "C" void kernel_launch(void* const* d_in, const int* in_sizes, int n_in,
                              void* d_out, int out_size, void* d_ws,
                              size_t ws_size, hipStream_t stream) {
  const float* query  = (const float*)d_in[0];
  const float* feat0  = (const float*)d_in[1];
  const float* feat1  = (const float*)d_in[2];
  const float* feat2  = (const float*)d_in[3];
  const float* feat3  = (const float*)d_in[4];
  const float* refp   = (const float*)d_in[5];
  const float* W_off  = (const float*)d_in[6];
  const float* b_off  = (const float*)d_in[7];
  const float* W_attn = (const float*)d_in[8];
  const float* b_attn = (const float*)d_in[9];
  const float* W_out  = (const float*)d_in[10];
  const float* b_out  = (const float*)d_in[11];

  float* out = (float*)d_out;                      // (B, Q, D)
  float* attn_out = out + (size_t)NB * NQ * ND;    // (B, Q, H, L, P)

  float* ws  = (float*)d_ws;
  float* fT0 = ws;                                     // unified feature ws
  float* fT1 = fT0 + (size_t)NB * 16384 * ND;
  float* fT2 = fT1 + (size_t)NB * 4096 * ND;
  float* fT3 = fT2 + (size_t)NB * 1024 * ND;
  float* pos = fT3 + (size_t)NB * 256 * ND;            // 4*8192*256
  float* agg = pos + (size_t)NB * NQ * ND;             // 4*8192*256

  transpose_k<<<dim3(512, 8, NB), 256, 0, stream>>>(feat0, fT0, 16384);
  transpose_k<<<dim3(128, 8, NB), 256, 0, stream>>>(feat1, fT1, 4096);
  transpose_k<<<dim3(32, 8, NB), 256, 0, stream>>>(feat2, fT2, 1024);
  transpose_k<<<dim3(8, 8, NB), 256, 0, stream>>>(feat3, fT3, 256);

  proj_k<<<dim3(NB * NQ / PQB), 256, 0, stream>>>(query, refp, W_off, b_off,
                                                  W_attn, b_attn, pos,
                                                  attn_out);
  sample_k<<<dim3(NB * NQ / 4), 256, 0, stream>>>(fT0, pos, attn_out, agg);
  out_k<<<dim3(NB * NQ / OQB), 256, 0, stream>>>(agg, W_out, b_out, out);
}